// Round 11
// baseline (141.742 us; speedup 1.0000x reference)
//
#include <hip/hip_runtime.h>
#include <cmath>

// ROUND 11: Round-6 anchor (110.7us) + ONE change: k_ffn+k_ln fused into k_out.
// k_front, k_mid, k_attn are byte-identical to Round 6.

typedef __bf16 bf16x8 __attribute__((ext_vector_type(8)));
typedef float f32x4 __attribute__((ext_vector_type(4)));

__device__ __forceinline__ float4 ld4(const float* p) { return *reinterpret_cast<const float4*>(p); }
__device__ __forceinline__ void st4(float* p, float4 v) { *reinterpret_cast<float4*>(p) = v; }
__device__ __forceinline__ void fma4(float4& a, float s, const float4& v) {
    a.x = fmaf(s, v.x, a.x); a.y = fmaf(s, v.y, a.y);
    a.z = fmaf(s, v.z, a.z); a.w = fmaf(s, v.w, a.w);
}
__device__ __forceinline__ float dot4(const float4& a, const float4& b) {
    return a.x*b.x + a.y*b.y + a.z*b.z + a.w*b.w;
}
__device__ __forceinline__ unsigned short f2bf(float f) {
    unsigned int x = __float_as_uint(f);
    unsigned int r = x + 0x7FFFu + ((x >> 16) & 1u);
    return (unsigned short)(r >> 16);
}
__device__ __forceinline__ ushort4 cvt4u(float4 a) {
    ushort4 u;
    u.x = f2bf(a.x); u.y = f2bf(a.y); u.z = f2bf(a.z); u.w = f2bf(a.w);
    return u;
}
__device__ __forceinline__ bf16x8 cvt8(float4 a, float4 b) {
    bf16x8 r;
    r[0] = (__bf16)a.x; r[1] = (__bf16)a.y; r[2] = (__bf16)a.z; r[3] = (__bf16)a.w;
    r[4] = (__bf16)b.x; r[5] = (__bf16)b.y; r[6] = (__bf16)b.z; r[7] = (__bf16)b.w;
    return r;
}

// Core 64x64 MFMA tile: 4 waves, wave wv owns rows [wv*16, wv*16+16) x 64 cols.
__device__ __forceinline__ void mfma_tile(
        const float* __restrict__ Abase, int ldA,
        const float* __restrict__ Bbase, int ldB,
        int K, int lane, f32x4 acc[4]) {
    int koff = (lane >> 4) * 8;
    int rr = lane & 15;
    const float* ap = Abase + rr * ldA + koff;
    const float* bp = Bbase + rr * ldB + koff;
#pragma unroll 2
    for (int k0 = 0; k0 < K; k0 += 32) {
        float4 a0  = ld4(ap + k0),            a1  = ld4(ap + k0 + 4);
        float4 b00 = ld4(bp + k0),            b01 = ld4(bp + k0 + 4);
        float4 b10 = ld4(bp + 16*ldB + k0),   b11 = ld4(bp + 16*ldB + k0 + 4);
        float4 b20 = ld4(bp + 32*ldB + k0),   b21 = ld4(bp + 32*ldB + k0 + 4);
        float4 b30 = ld4(bp + 48*ldB + k0),   b31 = ld4(bp + 48*ldB + k0 + 4);
        bf16x8 af = cvt8(a0, a1);
        acc[0] = __builtin_amdgcn_mfma_f32_16x16x32_bf16(af, cvt8(b00, b01), acc[0], 0, 0, 0);
        acc[1] = __builtin_amdgcn_mfma_f32_16x16x32_bf16(af, cvt8(b10, b11), acc[1], 0, 0, 0);
        acc[2] = __builtin_amdgcn_mfma_f32_16x16x32_bf16(af, cvt8(b20, b21), acc[2], 0, 0, 0);
        acc[3] = __builtin_amdgcn_mfma_f32_16x16x32_bf16(af, cvt8(b30, b31), acc[3], 0, 0, 0);
    }
}

// ---------------- K1: q/k/v projections (192 blocks) + Wr transpose (64 blocks) ----------------
__global__ __launch_bounds__(256) void k_front(
        const float* __restrict__ x,
        const float* __restrict__ Wq, const float* __restrict__ Wk, const float* __restrict__ Wv,
        const float* __restrict__ bq, const float* __restrict__ bk, const float* __restrict__ bv,
        const float* __restrict__ Wr,
        float* __restrict__ qw, float* __restrict__ kw, float* __restrict__ vw,
        float* __restrict__ wrt) {
    int id = blockIdx.x;
    int t = threadIdx.x;
    if (id < 192) {
        int mat = id >> 6, rem = id & 63;
        int m0 = (rem >> 3) * 64, n0 = (rem & 7) * 64;
        const float* W   = (mat == 0) ? Wq : (mat == 1) ? Wk : Wv;
        const float* bias= (mat == 0) ? bq : (mat == 1) ? bk : bv;
        float* out       = (mat == 0) ? qw : (mat == 1) ? kw : vw;
        int wv = t >> 6, lane = t & 63;
        f32x4 acc[4] = {{0,0,0,0},{0,0,0,0},{0,0,0,0},{0,0,0,0}};
        mfma_tile(x + (m0 + wv * 16) * 512, 512, W + n0 * 512, 512, 512, lane, acc);
        int h = n0 >> 6;
        int col = lane & 15, rbase = (lane >> 4) * 4;
#pragma unroll
        for (int c = 0; c < 4; c++) {
            int d = c * 16 + col;
            float bv_ = bias[n0 + d];
#pragma unroll
            for (int r = 0; r < 4; r++) {
                int m = m0 + wv * 16 + rbase + r;
                int b = m >> 8, i = m & 255;
                out[((b * 8 + h) * 256 + i) * 64 + d] = acc[c][r] + bv_;
            }
        }
    } else {
        __shared__ float tile[64][65];
        int id2 = id - 192;
        int n0 = (id2 >> 3) * 64, k0 = (id2 & 7) * 64;
        int tx = t & 63, ty = t >> 6;
#pragma unroll
        for (int r = 0; r < 16; r++) {
            int row = ty * 16 + r;
            tile[row][tx] = Wr[(n0 + row) * 512 + k0 + tx];
        }
        __syncthreads();
#pragma unroll
        for (int r = 0; r < 16; r++) {
            int row = ty * 16 + r;
            wrt[(k0 + row) * 512 + n0 + tx] = tile[tx][row];
        }
    }
}

// ---------------- K2: w-GEMM (512 blocks) + ac-GEMM (256 blocks), rank-1 terms inline ----------------
__global__ __launch_bounds__(256) void k_mid(
        const float* __restrict__ qw, const float* __restrict__ kw,
        const float* __restrict__ wrt,
        const float* __restrict__ u, const float* __restrict__ vb, const float* __restrict__ br,
        float* __restrict__ w_ws, float* __restrict__ ac_ws) {
    int id = blockIdx.x;
    int t = threadIdx.x, wv = t >> 6, lane = t & 63;
    __shared__ float red[8][64];
    if (id < 512) {
        int h = id >> 6, rem = id & 63;
        int m0 = (rem >> 3) * 64, n0 = (rem & 7) * 64;
        int b = m0 >> 8, i0 = m0 & 255;
        {
            int e = t & 63, grp = t >> 6;
            const float* wr_row = wrt + (size_t)(n0 + e) * 512 + h * 64 + grp * 16;
            const float* vbh = vb + h * 64 + grp * 16;
            float s = 0.f;
#pragma unroll
            for (int d = 0; d < 16; d += 4) s += dot4(ld4(wr_row + d), ld4(vbh + d));
            red[grp][e] = s;
        }
        __syncthreads();
        __shared__ float vwr_l[64];
        if (t < 64) vwr_l[t] = red[0][t] + red[1][t] + red[2][t] + red[3][t];
        f32x4 acc[4] = {{0,0,0,0},{0,0,0,0},{0,0,0,0},{0,0,0,0}};
        mfma_tile(qw + ((b * 8 + h) * 256 + i0 + wv * 16) * 64, 64,
                  wrt + (size_t)n0 * 512 + h * 64, 512, 64, lane, acc);
        __syncthreads();
        int col = lane & 15, rbase = (lane >> 4) * 4;
#pragma unroll
        for (int c = 0; c < 4; c++) {
            float vw_ = vwr_l[c * 16 + col];
            int n = n0 + c * 16 + col;
#pragma unroll
            for (int r = 0; r < 4; r++) {
                int m = m0 + wv * 16 + rbase + r;
                w_ws[((size_t)m * 8 + h) * 512 + n] = acc[c][r] + vw_;
            }
        }
    } else {
        int id2 = id - 512;
        int bh = id2 >> 4, rem2 = id2 & 15;
        int b = bh >> 3, h = bh & 7;
        int i0 = (rem2 >> 2) * 64, j0 = (rem2 & 3) * 64;
        {
            int xx = t & 63, grp = t >> 6;
            const float* qrow = qw + ((b * 8 + h) * 256 + i0 + xx) * 64 + grp * 16;
            const float* brh = br + h * 64 + grp * 16;
            const float* vbh = vb + h * 64 + grp * 16;
            float s = 0.f;
#pragma unroll
            for (int d = 0; d < 16; d += 4) {
                float4 q4 = ld4(qrow + d), b4 = ld4(brh + d), v4 = ld4(vbh + d);
                s += (q4.x + v4.x) * b4.x + (q4.y + v4.y) * b4.y
                   + (q4.z + v4.z) * b4.z + (q4.w + v4.w) * b4.w;
            }
            red[grp][xx] = s;
            const float* krow = kw + ((b * 8 + h) * 256 + j0 + xx) * 64 + grp * 16;
            const float* uh = u + h * 64 + grp * 16;
            s = 0.f;
#pragma unroll
            for (int d = 0; d < 16; d += 4) s += dot4(ld4(krow + d), ld4(uh + d));
            red[4 + grp][xx] = s;
        }
        __syncthreads();
        __shared__ float c_l[64], uk_l[64];
        if (t < 64) c_l[t] = red[0][t] + red[1][t] + red[2][t] + red[3][t];
        else if (t < 128) { int y = t - 64; uk_l[y] = red[4][y] + red[5][y] + red[6][y] + red[7][y]; }
        f32x4 acc[4] = {{0,0,0,0},{0,0,0,0},{0,0,0,0},{0,0,0,0}};
        mfma_tile(qw + ((b * 8 + h) * 256 + i0 + wv * 16) * 64, 64,
                  kw + ((b * 8 + h) * 256 + j0) * 64, 64, 64, lane, acc);
        __syncthreads();
        int col = lane & 15, rbase = (lane >> 4) * 4;
#pragma unroll
        for (int c = 0; c < 4; c++) {
            int j = j0 + c * 16 + col;
            float ukv = uk_l[c * 16 + col];
#pragma unroll
            for (int r = 0; r < 4; r++) {
                int ii = wv * 16 + rbase + r;
                ac_ws[((b * 256 + i0 + ii) * 8 + h) * 256 + j] = acc[c][r] + ukv + c_l[ii];
            }
        }
    }
}

// ---------------- K3: fused B_D (LDS-staged MFMA) + softmax + PV (Round-6 version) ----------------
__global__ __launch_bounds__(512, 4) void k_attn(
        const float* __restrict__ pos, const float* __restrict__ w_ws,
        const float* __restrict__ ac_ws, const float* __restrict__ vw,
        const int* __restrict__ seq_mask, float* __restrict__ ctx) {
    int bi = blockIdx.x;
    int b = bi >> 8, i = bi & 255;
    int t = threadIdx.x;
    int wv = t >> 6, lane = t & 63;
    __shared__ unsigned short wl[8 * 512];
    __shared__ float sc[8][256];
    __shared__ unsigned short stage[8][4096];

    {
        int h = t >> 6;
        int e0 = (t & 63) * 8;
        const float* src = w_ws + ((size_t)bi * 8 + h) * 512 + e0;
        float4 a = ld4(src);
        float4 c = ld4(src + 4);
        *reinterpret_cast<ushort4*>(&wl[h * 512 + e0])     = cvt4u(a);
        *reinterpret_cast<ushort4*>(&wl[h * 512 + e0 + 4]) = cvt4u(c);
    }
    __syncthreads();

    const float* pb = pos + (size_t)bi * (256 * 512);
    int jbase = wv * 32;
    unsigned short* sb = &stage[wv][0];
    int arow = lane & 15;
    int koff = (lane >> 4) * 8;

#pragma unroll
    for (int jt = 0; jt < 2; jt++) {
        f32x4 acc = {0, 0, 0, 0};
#pragma unroll
        for (int eh = 0; eh < 2; eh++) {
            const float* src = pb + (size_t)(jbase + jt * 16) * 512 + eh * 256 + lane * 4;
            float4 tmp[16];
#pragma unroll
            for (int s = 0; s < 16; s++) tmp[s] = ld4(src + s * 512);
#pragma unroll
            for (int s = 0; s < 16; s++) {
                *reinterpret_cast<ushort4*>(&sb[s * 256 + lane * 4]) = cvt4u(tmp[s]);
            }
#pragma unroll
            for (int es = 0; es < 8; es++) {
                bf16x8 af = *reinterpret_cast<const bf16x8*>(&sb[arow * 256 + es * 32 + koff]);
                bf16x8 bf = *reinterpret_cast<const bf16x8*>(&wl[(lane & 7) * 512 + (eh * 8 + es) * 32 + koff]);
                acc = __builtin_amdgcn_mfma_f32_16x16x32_bf16(af, bf, acc, 0, 0, 0);
            }
        }
        int h = lane & 15;
        int rbase = (lane >> 4) * 4;
        if (h < 8) {
#pragma unroll
            for (int r = 0; r < 4; r++) sc[h][jbase + jt * 16 + rbase + r] = acc[r];
        }
    }
    __syncthreads();

    {
        int h = wv;
        const float* acrow = ac_ws + ((b * 256 + i) * 8 + h) * 256;
        float vals[4];
        float mx = -INFINITY;
#pragma unroll
        for (int r = 0; r < 4; r++) {
            int j = lane + r * 64;
            float s = (sc[h][j] + acrow[j]) * 0.125f;
            if (seq_mask[b * 256 + j] == 0) s = -1e15f;
            vals[r] = s;
            mx = fmaxf(mx, s);
        }
#pragma unroll
        for (int m = 32; m >= 1; m >>= 1) mx = fmaxf(mx, __shfl_xor(mx, m, 64));
        float sum = 0.f;
#pragma unroll
        for (int r = 0; r < 4; r++) { vals[r] = __expf(vals[r] - mx); sum += vals[r]; }
#pragma unroll
        for (int m = 32; m >= 1; m >>= 1) sum += __shfl_xor(sum, m, 64);
        float inv = 1.0f / sum;
#pragma unroll
        for (int r = 0; r < 4; r++) sc[h][lane + r * 64] = vals[r] * inv;
    }

    float4* part = reinterpret_cast<float4*>(&stage[0][0]);
    {
        int h = wv;
        int d4 = (lane & 15) * 4;
        int js = lane >> 4;
        const float* vbase = vw + (size_t)(b * 8 + h) * 256 * 64 + d4;
        float4 acc = {0, 0, 0, 0};
#pragma unroll 2
        for (int r = 0; r < 64; r += 4) {
            int j = js * 64 + r;
            float p0 = sc[h][j + 0], p1 = sc[h][j + 1];
            float p2 = sc[h][j + 2], p3 = sc[h][j + 3];
            float4 v0 = ld4(vbase + (size_t)(j + 0) * 64);
            float4 v1 = ld4(vbase + (size_t)(j + 1) * 64);
            float4 v2 = ld4(vbase + (size_t)(j + 2) * 64);
            float4 v3 = ld4(vbase + (size_t)(j + 3) * 64);
            fma4(acc, p0, v0); fma4(acc, p1, v1);
            fma4(acc, p2, v2); fma4(acc, p3, v3);
        }
        part[(h * 4 + js) * 16 + (lane & 15)] = acc;
    }
    {
        int h = wv;
        if ((lane >> 4) == 0) {
            int l = lane & 15;
            float4 a0 = part[(h * 4 + 0) * 16 + l], a1 = part[(h * 4 + 1) * 16 + l];
            float4 a2 = part[(h * 4 + 2) * 16 + l], a3 = part[(h * 4 + 3) * 16 + l];
            float4 o;
            o.x = a0.x + a1.x + a2.x + a3.x;
            o.y = a0.y + a1.y + a2.y + a3.y;
            o.z = a0.z + a1.z + a2.z + a3.z;
            o.w = a0.w + a1.w + a2.w + a3.w;
            st4(ctx + (size_t)(b * 256 + i) * 512 + h * 64 + l * 4, o);
        }
    }
}

// ---------------- K4: FFN GEMM + bias + residual + LayerNorm fused ----------------
// 32 blocks x 256 thr; block = 16 full rows; wave wv covers cols [wv*128, +128)
__global__ __launch_bounds__(256) void k_out(
        const float* __restrict__ A, const float* __restrict__ Wf,
        const float* __restrict__ bf, const float* __restrict__ resid,
        const float* __restrict__ gamma, const float* __restrict__ beta,
        float* __restrict__ outp) {
    int m0 = blockIdx.x * 16;
    int t = threadIdx.x, wv = t >> 6, lane = t & 63;
    int rr = lane & 15, koff = (lane >> 4) * 8;
    int col = lane & 15, rbase = (lane >> 4) * 4;
    const float* ap = A + (size_t)(m0 + rr) * 512 + koff;
    f32x4 acc[8];
#pragma unroll
    for (int nt = 0; nt < 8; nt++) acc[nt] = (f32x4){0, 0, 0, 0};
#pragma unroll 2
    for (int k0 = 0; k0 < 512; k0 += 32) {
        float4 a0 = ld4(ap + k0), a1 = ld4(ap + k0 + 4);
        bf16x8 af = cvt8(a0, a1);
#pragma unroll
        for (int nt = 0; nt < 8; nt++) {
            int n = wv * 128 + nt * 16 + rr;
            float4 b0 = ld4(&Wf[(size_t)n * 512 + k0 + koff]);
            float4 b1 = ld4(&Wf[(size_t)n * 512 + k0 + koff + 4]);
            acc[nt] = __builtin_amdgcn_mfma_f32_16x16x32_bf16(af, cvt8(b0, b1), acc[nt], 0, 0, 0);
        }
    }
    float vals[8][4];
    float psum[4] = {0, 0, 0, 0}, psq[4] = {0, 0, 0, 0};
#pragma unroll
    for (int nt = 0; nt < 8; nt++) {
        int n = wv * 128 + nt * 16 + col;
        float bfn = bf[n];
#pragma unroll
        for (int r = 0; r < 4; r++) {
            int m = m0 + rbase + r;
            float v = acc[nt][r] + bfn + resid[(size_t)m * 512 + n];
            vals[nt][r] = v;
            psum[r] += v;
            psq[r] += v * v;
        }
    }
#pragma unroll
    for (int msk = 1; msk < 16; msk <<= 1) {
#pragma unroll
        for (int r = 0; r < 4; r++) {
            psum[r] += __shfl_xor(psum[r], msk, 64);
            psq[r]  += __shfl_xor(psq[r],  msk, 64);
        }
    }
    __shared__ float redS[16][4], redQ[16][4];
    if ((lane & 15) == 0) {
#pragma unroll
        for (int r = 0; r < 4; r++) {
            redS[rbase + r][wv] = psum[r];
            redQ[rbase + r][wv] = psq[r];
        }
    }
    __syncthreads();
    float mu[4], rstd[4];
#pragma unroll
    for (int r = 0; r < 4; r++) {
        int row = rbase + r;
        float s = redS[row][0] + redS[row][1] + redS[row][2] + redS[row][3];
        float q = redQ[row][0] + redQ[row][1] + redQ[row][2] + redQ[row][3];
        float m_ = s * (1.0f / 512.0f);
        float var = q * (1.0f / 512.0f) - m_ * m_;
        mu[r] = m_;
        rstd[r] = rsqrtf(var + 1e-12f);
    }
#pragma unroll
    for (int nt = 0; nt < 8; nt++) {
        int n = wv * 128 + nt * 16 + col;
        float g = gamma[n], be = beta[n];
#pragma unroll
        for (int r = 0; r < 4; r++) {
            int m = m0 + rbase + r;
            outp[(size_t)m * 512 + n] = (vals[nt][r] - mu[r]) * rstd[r] * g + be;
        }
    }
}

extern "C" void kernel_launch(void* const* d_in, const int* in_sizes, int n_in,
                              void* d_out, int out_size, void* d_ws, size_t ws_size,
                              hipStream_t stream) {
    const float* x     = (const float*)d_in[0];
    const float* pos   = (const float*)d_in[1];
    const int*   smask = (const int*)d_in[2];
    const float* Wq = (const float*)d_in[3];
    const float* bq = (const float*)d_in[4];
    const float* Wk = (const float*)d_in[5];
    const float* bk = (const float*)d_in[6];
    const float* Wv = (const float*)d_in[7];
    const float* bv = (const float*)d_in[8];
    const float* Wr = (const float*)d_in[9];
    const float* br = (const float*)d_in[10];
    const float* u  = (const float*)d_in[11];
    const float* vb = (const float*)d_in[12];
    const float* Wf = (const float*)d_in[13];
    const float* bf = (const float*)d_in[14];
    const float* gamma = (const float*)d_in[15];
    const float* beta  = (const float*)d_in[16];
    float* out = (float*)d_out;

    float* ws = (float*)d_ws;
    float* q_ws   = ws;                       // 262144 f
    float* k_ws   = q_ws  + 262144;           // 262144 f
    float* v_ws   = k_ws  + 262144;           // 262144 f
    float* w_ws   = v_ws  + 262144;           // 2097152 f
    float* ac_ws  = w_ws  + 2097152;          // 1048576 f
    float* ctx_ws = ac_ws + 1048576;          // 262144 f
    float* wrt_ws = ctx_ws + 262144;          // 262144 f

    k_front<<<dim3(256), 256, 0, stream>>>(x, Wq, Wk, Wv, bq, bk, bv, Wr,
                                           q_ws, k_ws, v_ws, wrt_ws);
    k_mid<<<dim3(768), 256, 0, stream>>>(q_ws, k_ws, wrt_ws, u, vb, br, w_ws, ac_ws);
    k_attn<<<dim3(512), 512, 0, stream>>>(pos, w_ws, ac_ws, v_ws, smask, ctx_ws);
    k_out<<<dim3(32), 256, 0, stream>>>(ctx_ws, Wf, bf, x, gamma, beta, out);
}

// Round 12
// 109.563 us; speedup vs baseline: 1.2937x; 1.2937x over previous
//
#include <hip/hip_runtime.h>
#include <cmath>

// ROUND 12: Round-6 anchor + ONE change: rank-1 terms (c, uk, vwr) moved from
// k_mid's uncoalesced phases into k_front epilogues (data already in reg/LDS).
// k_mid is now pure MFMA. k_attn, k_ffn, k_ln byte-identical to Round 6.

typedef __bf16 bf16x8 __attribute__((ext_vector_type(8)));
typedef float f32x4 __attribute__((ext_vector_type(4)));

__device__ __forceinline__ float4 ld4(const float* p) { return *reinterpret_cast<const float4*>(p); }
__device__ __forceinline__ void st4(float* p, float4 v) { *reinterpret_cast<float4*>(p) = v; }
__device__ __forceinline__ void fma4(float4& a, float s, const float4& v) {
    a.x = fmaf(s, v.x, a.x); a.y = fmaf(s, v.y, a.y);
    a.z = fmaf(s, v.z, a.z); a.w = fmaf(s, v.w, a.w);
}
__device__ __forceinline__ float dot4(const float4& a, const float4& b) {
    return a.x*b.x + a.y*b.y + a.z*b.z + a.w*b.w;
}
__device__ __forceinline__ unsigned short f2bf(float f) {
    unsigned int x = __float_as_uint(f);
    unsigned int r = x + 0x7FFFu + ((x >> 16) & 1u);
    return (unsigned short)(r >> 16);
}
__device__ __forceinline__ ushort4 cvt4u(float4 a) {
    ushort4 u;
    u.x = f2bf(a.x); u.y = f2bf(a.y); u.z = f2bf(a.z); u.w = f2bf(a.w);
    return u;
}
__device__ __forceinline__ bf16x8 cvt8(float4 a, float4 b) {
    bf16x8 r;
    r[0] = (__bf16)a.x; r[1] = (__bf16)a.y; r[2] = (__bf16)a.z; r[3] = (__bf16)a.w;
    r[4] = (__bf16)b.x; r[5] = (__bf16)b.y; r[6] = (__bf16)b.z; r[7] = (__bf16)b.w;
    return r;
}

// Core 64x64 MFMA tile: 4 waves, wave wv owns rows [wv*16, wv*16+16) x 64 cols.
__device__ __forceinline__ void mfma_tile(
        const float* __restrict__ Abase, int ldA,
        const float* __restrict__ Bbase, int ldB,
        int K, int lane, f32x4 acc[4]) {
    int koff = (lane >> 4) * 8;
    int rr = lane & 15;
    const float* ap = Abase + rr * ldA + koff;
    const float* bp = Bbase + rr * ldB + koff;
#pragma unroll 2
    for (int k0 = 0; k0 < K; k0 += 32) {
        float4 a0  = ld4(ap + k0),            a1  = ld4(ap + k0 + 4);
        float4 b00 = ld4(bp + k0),            b01 = ld4(bp + k0 + 4);
        float4 b10 = ld4(bp + 16*ldB + k0),   b11 = ld4(bp + 16*ldB + k0 + 4);
        float4 b20 = ld4(bp + 32*ldB + k0),   b21 = ld4(bp + 32*ldB + k0 + 4);
        float4 b30 = ld4(bp + 48*ldB + k0),   b31 = ld4(bp + 48*ldB + k0 + 4);
        bf16x8 af = cvt8(a0, a1);
        acc[0] = __builtin_amdgcn_mfma_f32_16x16x32_bf16(af, cvt8(b00, b01), acc[0], 0, 0, 0);
        acc[1] = __builtin_amdgcn_mfma_f32_16x16x32_bf16(af, cvt8(b10, b11), acc[1], 0, 0, 0);
        acc[2] = __builtin_amdgcn_mfma_f32_16x16x32_bf16(af, cvt8(b20, b21), acc[2], 0, 0, 0);
        acc[3] = __builtin_amdgcn_mfma_f32_16x16x32_bf16(af, cvt8(b30, b31), acc[3], 0, 0, 0);
    }
}

// ---------------- K1: q/k/v projections (192) + Wr transpose (64) ----------------
// q-blocks emit c[bhi]; k-blocks emit uk[bhj]; transpose blocks emit vwr[h,e].
__global__ __launch_bounds__(256) void k_front(
        const float* __restrict__ x,
        const float* __restrict__ Wq, const float* __restrict__ Wk, const float* __restrict__ Wv,
        const float* __restrict__ bq, const float* __restrict__ bk, const float* __restrict__ bv,
        const float* __restrict__ Wr,
        const float* __restrict__ u, const float* __restrict__ vbv, const float* __restrict__ br,
        float* __restrict__ qw, float* __restrict__ kw, float* __restrict__ vw,
        float* __restrict__ wrt,
        float* __restrict__ c_ws, float* __restrict__ uk_ws, float* __restrict__ vwr_ws) {
    int id = blockIdx.x;
    int t = threadIdx.x;
    if (id < 192) {
        int mat = id >> 6, rem = id & 63;
        int m0 = (rem >> 3) * 64, n0 = (rem & 7) * 64;
        const float* W   = (mat == 0) ? Wq : (mat == 1) ? Wk : Wv;
        const float* bias= (mat == 0) ? bq : (mat == 1) ? bk : bv;
        float* out       = (mat == 0) ? qw : (mat == 1) ? kw : vw;
        int wv = t >> 6, lane = t & 63;
        f32x4 acc[4] = {{0,0,0,0},{0,0,0,0},{0,0,0,0},{0,0,0,0}};
        mfma_tile(x + (m0 + wv * 16) * 512, 512, W + n0 * 512, 512, 512, lane, acc);
        int h = n0 >> 6;
        int col = lane & 15, rbase = (lane >> 4) * 4;
        float rpart[4] = {0, 0, 0, 0};
#pragma unroll
        for (int c = 0; c < 4; c++) {
            int d = c * 16 + col;          // within-head col
            float bv_ = bias[n0 + d];
            float vbd = vbv[n0 + d];
            float brd = br[n0 + d];
            float ud  = u[n0 + d];
#pragma unroll
            for (int r = 0; r < 4; r++) {
                int m = m0 + wv * 16 + rbase + r;
                int b = m >> 8, i = m & 255;
                float val = acc[c][r] + bv_;
                out[((b * 8 + h) * 256 + i) * 64 + d] = val;
                if (mat == 0) rpart[r] += (val + vbd) * brd;   // c term
                else if (mat == 1) rpart[r] += val * ud;       // uk term
            }
        }
        if (mat < 2) {
#pragma unroll
            for (int msk = 1; msk < 16; msk <<= 1) {
#pragma unroll
                for (int r = 0; r < 4; r++) rpart[r] += __shfl_xor(rpart[r], msk, 64);
            }
            if (col == 0) {
                float* dst = (mat == 0) ? c_ws : uk_ws;
#pragma unroll
                for (int r = 0; r < 4; r++) {
                    int m = m0 + wv * 16 + rbase + r;
                    int b = m >> 8, i = m & 255;
                    dst[(b * 8 + h) * 256 + i] = rpart[r];
                }
            }
        }
    } else {
        // transpose Wr[n][k] -> wrt[k][n]; also vwr[h,e] = vb_h . Wr[h*64:, e]
        __shared__ float tile[64][65];
        __shared__ float vpart[4][64];
        int id2 = id - 192;
        int n0 = (id2 >> 3) * 64, k0 = (id2 & 7) * 64;
        int h = n0 >> 6;
        int tx = t & 63, ty = t >> 6;
#pragma unroll
        for (int r = 0; r < 16; r++) {
            int row = ty * 16 + r;
            tile[row][tx] = Wr[(n0 + row) * 512 + k0 + tx];
        }
        __syncthreads();
#pragma unroll
        for (int r = 0; r < 16; r++) {
            int row = ty * 16 + r;
            wrt[(k0 + row) * 512 + n0 + tx] = tile[tx][row];
        }
        // vwr partial: group ty sums rows [ty*16, ty*16+16)
        float s = 0.f;
#pragma unroll
        for (int r = 0; r < 16; r++) s += vbv[n0 + ty * 16 + r] * tile[ty * 16 + r][tx];
        vpart[ty][tx] = s;
        __syncthreads();
        if (t < 64) vwr_ws[h * 512 + k0 + t] = vpart[0][t] + vpart[1][t] + vpart[2][t] + vpart[3][t];
    }
}

// ---------------- K2: w-GEMM (512) + ac-GEMM (256), pure MFMA ----------------
__global__ __launch_bounds__(256) void k_mid(
        const float* __restrict__ qw, const float* __restrict__ kw,
        const float* __restrict__ wrt,
        const float* __restrict__ c_ws, const float* __restrict__ uk_ws,
        const float* __restrict__ vwr_ws,
        float* __restrict__ w_ws, float* __restrict__ ac_ws) {
    int id = blockIdx.x;
    int t = threadIdx.x, wv = t >> 6, lane = t & 63;
    int col = lane & 15, rbase = (lane >> 4) * 4;
    if (id < 512) {
        int h = id >> 6, rem = id & 63;
        int m0 = (rem >> 3) * 64, n0 = (rem & 7) * 64;
        int b = m0 >> 8, i0 = m0 & 255;
        f32x4 acc[4] = {{0,0,0,0},{0,0,0,0},{0,0,0,0},{0,0,0,0}};
        mfma_tile(qw + ((b * 8 + h) * 256 + i0 + wv * 16) * 64, 64,
                  wrt + (size_t)n0 * 512 + h * 64, 512, 64, lane, acc);
#pragma unroll
        for (int c = 0; c < 4; c++) {
            int n = n0 + c * 16 + col;
            float vw_ = vwr_ws[h * 512 + n];
#pragma unroll
            for (int r = 0; r < 4; r++) {
                int m = m0 + wv * 16 + rbase + r;
                w_ws[((size_t)m * 8 + h) * 512 + n] = acc[c][r] + vw_;
            }
        }
    } else {
        int id2 = id - 512;
        int bh = id2 >> 4, rem2 = id2 & 15;
        int b = bh >> 3, h = bh & 7;
        int i0 = (rem2 >> 2) * 64, j0 = (rem2 & 3) * 64;
        f32x4 acc[4] = {{0,0,0,0},{0,0,0,0},{0,0,0,0},{0,0,0,0}};
        mfma_tile(qw + ((b * 8 + h) * 256 + i0 + wv * 16) * 64, 64,
                  kw + ((b * 8 + h) * 256 + j0) * 64, 64, 64, lane, acc);
#pragma unroll
        for (int c = 0; c < 4; c++) {
            int j = j0 + c * 16 + col;
            float ukv = uk_ws[(b * 8 + h) * 256 + j];
#pragma unroll
            for (int r = 0; r < 4; r++) {
                int ii = i0 + wv * 16 + rbase + r;
                float ci = c_ws[(b * 8 + h) * 256 + ii];
                ac_ws[((size_t)(b * 256 + ii) * 8 + h) * 256 + j] = acc[c][r] + ukv + ci;
            }
        }
    }
}

// ---------------- K3: fused B_D (LDS-staged MFMA) + softmax + PV (Round-6) ----------------
__global__ __launch_bounds__(512, 4) void k_attn(
        const float* __restrict__ pos, const float* __restrict__ w_ws,
        const float* __restrict__ ac_ws, const float* __restrict__ vw,
        const int* __restrict__ seq_mask, float* __restrict__ ctx) {
    int bi = blockIdx.x;
    int b = bi >> 8, i = bi & 255;
    int t = threadIdx.x;
    int wv = t >> 6, lane = t & 63;
    __shared__ unsigned short wl[8 * 512];
    __shared__ float sc[8][256];
    __shared__ unsigned short stage[8][4096];

    {
        int h = t >> 6;
        int e0 = (t & 63) * 8;
        const float* src = w_ws + ((size_t)bi * 8 + h) * 512 + e0;
        float4 a = ld4(src);
        float4 c = ld4(src + 4);
        *reinterpret_cast<ushort4*>(&wl[h * 512 + e0])     = cvt4u(a);
        *reinterpret_cast<ushort4*>(&wl[h * 512 + e0 + 4]) = cvt4u(c);
    }
    __syncthreads();

    const float* pb = pos + (size_t)bi * (256 * 512);
    int jbase = wv * 32;
    unsigned short* sb = &stage[wv][0];
    int arow = lane & 15;
    int koff = (lane >> 4) * 8;

#pragma unroll
    for (int jt = 0; jt < 2; jt++) {
        f32x4 acc = {0, 0, 0, 0};
#pragma unroll
        for (int eh = 0; eh < 2; eh++) {
            const float* src = pb + (size_t)(jbase + jt * 16) * 512 + eh * 256 + lane * 4;
            float4 tmp[16];
#pragma unroll
            for (int s = 0; s < 16; s++) tmp[s] = ld4(src + s * 512);
#pragma unroll
            for (int s = 0; s < 16; s++) {
                *reinterpret_cast<ushort4*>(&sb[s * 256 + lane * 4]) = cvt4u(tmp[s]);
            }
#pragma unroll
            for (int es = 0; es < 8; es++) {
                bf16x8 af = *reinterpret_cast<const bf16x8*>(&sb[arow * 256 + es * 32 + koff]);
                bf16x8 bf = *reinterpret_cast<const bf16x8*>(&wl[(lane & 7) * 512 + (eh * 8 + es) * 32 + koff]);
                acc = __builtin_amdgcn_mfma_f32_16x16x32_bf16(af, bf, acc, 0, 0, 0);
            }
        }
        int h = lane & 15;
        int rbase = (lane >> 4) * 4;
        if (h < 8) {
#pragma unroll
            for (int r = 0; r < 4; r++) sc[h][jbase + jt * 16 + rbase + r] = acc[r];
        }
    }
    __syncthreads();

    {
        int h = wv;
        const float* acrow = ac_ws + ((b * 256 + i) * 8 + h) * 256;
        float vals[4];
        float mx = -INFINITY;
#pragma unroll
        for (int r = 0; r < 4; r++) {
            int j = lane + r * 64;
            float s = (sc[h][j] + acrow[j]) * 0.125f;
            if (seq_mask[b * 256 + j] == 0) s = -1e15f;
            vals[r] = s;
            mx = fmaxf(mx, s);
        }
#pragma unroll
        for (int m = 32; m >= 1; m >>= 1) mx = fmaxf(mx, __shfl_xor(mx, m, 64));
        float sum = 0.f;
#pragma unroll
        for (int r = 0; r < 4; r++) { vals[r] = __expf(vals[r] - mx); sum += vals[r]; }
#pragma unroll
        for (int m = 32; m >= 1; m >>= 1) sum += __shfl_xor(sum, m, 64);
        float inv = 1.0f / sum;
#pragma unroll
        for (int r = 0; r < 4; r++) sc[h][lane + r * 64] = vals[r] * inv;
    }

    float4* part = reinterpret_cast<float4*>(&stage[0][0]);
    {
        int h = wv;
        int d4 = (lane & 15) * 4;
        int js = lane >> 4;
        const float* vbase = vw + (size_t)(b * 8 + h) * 256 * 64 + d4;
        float4 acc = {0, 0, 0, 0};
#pragma unroll 2
        for (int r = 0; r < 64; r += 4) {
            int j = js * 64 + r;
            float p0 = sc[h][j + 0], p1 = sc[h][j + 1];
            float p2 = sc[h][j + 2], p3 = sc[h][j + 3];
            float4 v0 = ld4(vbase + (size_t)(j + 0) * 64);
            float4 v1 = ld4(vbase + (size_t)(j + 1) * 64);
            float4 v2 = ld4(vbase + (size_t)(j + 2) * 64);
            float4 v3 = ld4(vbase + (size_t)(j + 3) * 64);
            fma4(acc, p0, v0); fma4(acc, p1, v1);
            fma4(acc, p2, v2); fma4(acc, p3, v3);
        }
        part[(h * 4 + js) * 16 + (lane & 15)] = acc;
    }
    {
        int h = wv;
        if ((lane >> 4) == 0) {
            int l = lane & 15;
            float4 a0 = part[(h * 4 + 0) * 16 + l], a1 = part[(h * 4 + 1) * 16 + l];
            float4 a2 = part[(h * 4 + 2) * 16 + l], a3 = part[(h * 4 + 3) * 16 + l];
            float4 o;
            o.x = a0.x + a1.x + a2.x + a3.x;
            o.y = a0.y + a1.y + a2.y + a3.y;
            o.z = a0.z + a1.z + a2.z + a3.z;
            o.w = a0.w + a1.w + a2.w + a3.w;
            st4(ctx + (size_t)(b * 256 + i) * 512 + h * 64 + l * 4, o);
        }
    }
}

// ---------------- K4: FFN GEMM + bias + residual (Round-6) ----------------
__global__ __launch_bounds__(256) void k_ffn(
        const float* __restrict__ A, const float* __restrict__ Wf,
        const float* __restrict__ bias, const float* __restrict__ resid,
        float* __restrict__ outp) {
    int m0 = blockIdx.x * 64, n0 = blockIdx.y * 64;
    int t = threadIdx.x, wv = t >> 6, lane = t & 63;
    f32x4 acc[4] = {{0,0,0,0},{0,0,0,0},{0,0,0,0},{0,0,0,0}};
    mfma_tile(A + (m0 + wv * 16) * 512, 512, Wf + n0 * 512, 512, 512, lane, acc);
    int col = lane & 15, rbase = (lane >> 4) * 4;
#pragma unroll
    for (int c = 0; c < 4; c++) {
        int n = n0 + c * 16 + col;
        float bv_ = bias[n];
#pragma unroll
        for (int r = 0; r < 4; r++) {
            int m = m0 + wv * 16 + rbase + r;
            outp[m * 512 + n] = acc[c][r] + bv_ + resid[m * 512 + n];
        }
    }
}

// ---------------- K5: LayerNorm (Round-6) ----------------
__global__ __launch_bounds__(256) void k_ln(
        const float* __restrict__ tmp, const float* __restrict__ gamma,
        const float* __restrict__ beta, float* __restrict__ out) {
    int m = blockIdx.x, t = threadIdx.x;
    int wv = t >> 6, lane = t & 63;
    float2 xv = *reinterpret_cast<const float2*>(&tmp[m * 512 + t * 2]);
    __shared__ float red[4];
    float s = xv.x + xv.y;
#pragma unroll
    for (int k = 32; k >= 1; k >>= 1) s += __shfl_xor(s, k, 64);
    if (lane == 0) red[wv] = s;
    __syncthreads();
    float mu = (red[0] + red[1] + red[2] + red[3]) * (1.0f / 512.0f);
    __syncthreads();
    float dx = xv.x - mu, dy = xv.y - mu;
    float vs = dx * dx + dy * dy;
#pragma unroll
    for (int k = 32; k >= 1; k >>= 1) vs += __shfl_xor(vs, k, 64);
    if (lane == 0) red[wv] = vs;
    __syncthreads();
    float var = (red[0] + red[1] + red[2] + red[3]) * (1.0f / 512.0f);
    float rstd = rsqrtf(var + 1e-12f);
    float2 g = *reinterpret_cast<const float2*>(&gamma[t * 2]);
    float2 be = *reinterpret_cast<const float2*>(&beta[t * 2]);
    float2 o;
    o.x = dx * rstd * g.x + be.x;
    o.y = dy * rstd * g.y + be.y;
    *reinterpret_cast<float2*>(&out[m * 512 + t * 2]) = o;
}

extern "C" void kernel_launch(void* const* d_in, const int* in_sizes, int n_in,
                              void* d_out, int out_size, void* d_ws, size_t ws_size,
                              hipStream_t stream) {
    const float* x     = (const float*)d_in[0];
    const float* pos   = (const float*)d_in[1];
    const int*   smask = (const int*)d_in[2];
    const float* Wq = (const float*)d_in[3];
    const float* bq = (const float*)d_in[4];
    const float* Wk = (const float*)d_in[5];
    const float* bk = (const float*)d_in[6];
    const float* Wv = (const float*)d_in[7];
    const float* bv = (const float*)d_in[8];
    const float* Wr = (const float*)d_in[9];
    const float* br = (const float*)d_in[10];
    const float* u  = (const float*)d_in[11];
    const float* vb = (const float*)d_in[12];
    const float* Wf = (const float*)d_in[13];
    const float* bf = (const float*)d_in[14];
    const float* gamma = (const float*)d_in[15];
    const float* beta  = (const float*)d_in[16];
    float* out = (float*)d_out;

    float* ws = (float*)d_ws;
    float* q_ws   = ws;                       // 262144 f
    float* k_ws   = q_ws  + 262144;           // 262144 f
    float* v_ws   = k_ws  + 262144;           // 262144 f
    float* w_ws   = v_ws  + 262144;           // 2097152 f
    float* ac_ws  = w_ws  + 2097152;          // 1048576 f
    float* ctx_ws = ac_ws + 1048576;          // 262144 f
    float* tmp_ws = ctx_ws + 262144;          // 262144 f
    float* wrt_ws = tmp_ws + 262144;          // 262144 f
    float* c_ws   = wrt_ws + 262144;          // 4096 f
    float* uk_ws  = c_ws  + 4096;             // 4096 f
    float* vwr_ws = uk_ws + 4096;             // 4096 f

    k_front<<<dim3(256), 256, 0, stream>>>(x, Wq, Wk, Wv, bq, bk, bv, Wr, u, vb, br,
                                           q_ws, k_ws, v_ws, wrt_ws, c_ws, uk_ws, vwr_ws);
    k_mid<<<dim3(768), 256, 0, stream>>>(q_ws, k_ws, wrt_ws, c_ws, uk_ws, vwr_ws, w_ws, ac_ws);
    k_attn<<<dim3(512), 512, 0, stream>>>(pos, w_ws, ac_ws, v_ws, smask, ctx_ws);
    k_ffn<<<dim3(8, 8), 256, 0, stream>>>(ctx_ws, Wf, bf, x, tmp_ws);
    k_ln<<<dim3(512), 256, 0, stream>>>(tmp_ws, gamma, beta, out);
}

// Round 13
// 108.109 us; speedup vs baseline: 1.3111x; 1.0135x over previous
//
#include <hip/hip_runtime.h>
#include <cmath>

// ROUND 13: R12 anchor (109.6us) + k_attn-only change: conflict-free LDS
// (B-frags in fragment order, A-stage 128e chunks w/ 256B row stride) and
// LDS diet 80->48KB (3 blocks/CU if VGPR permits). All other kernels identical.

typedef __bf16 bf16x8 __attribute__((ext_vector_type(8)));
typedef float f32x4 __attribute__((ext_vector_type(4)));

__device__ __forceinline__ float4 ld4(const float* p) { return *reinterpret_cast<const float4*>(p); }
__device__ __forceinline__ void st4(float* p, float4 v) { *reinterpret_cast<float4*>(p) = v; }
__device__ __forceinline__ void fma4(float4& a, float s, const float4& v) {
    a.x = fmaf(s, v.x, a.x); a.y = fmaf(s, v.y, a.y);
    a.z = fmaf(s, v.z, a.z); a.w = fmaf(s, v.w, a.w);
}
__device__ __forceinline__ float dot4(const float4& a, const float4& b) {
    return a.x*b.x + a.y*b.y + a.z*b.z + a.w*b.w;
}
__device__ __forceinline__ unsigned short f2bf(float f) {
    unsigned int x = __float_as_uint(f);
    unsigned int r = x + 0x7FFFu + ((x >> 16) & 1u);
    return (unsigned short)(r >> 16);
}
__device__ __forceinline__ ushort4 cvt4u(float4 a) {
    ushort4 u;
    u.x = f2bf(a.x); u.y = f2bf(a.y); u.z = f2bf(a.z); u.w = f2bf(a.w);
    return u;
}
__device__ __forceinline__ bf16x8 cvt8(float4 a, float4 b) {
    bf16x8 r;
    r[0] = (__bf16)a.x; r[1] = (__bf16)a.y; r[2] = (__bf16)a.z; r[3] = (__bf16)a.w;
    r[4] = (__bf16)b.x; r[5] = (__bf16)b.y; r[6] = (__bf16)b.z; r[7] = (__bf16)b.w;
    return r;
}

// Core 64x64 MFMA tile: 4 waves, wave wv owns rows [wv*16, wv*16+16) x 64 cols.
__device__ __forceinline__ void mfma_tile(
        const float* __restrict__ Abase, int ldA,
        const float* __restrict__ Bbase, int ldB,
        int K, int lane, f32x4 acc[4]) {
    int koff = (lane >> 4) * 8;
    int rr = lane & 15;
    const float* ap = Abase + rr * ldA + koff;
    const float* bp = Bbase + rr * ldB + koff;
#pragma unroll 2
    for (int k0 = 0; k0 < K; k0 += 32) {
        float4 a0  = ld4(ap + k0),            a1  = ld4(ap + k0 + 4);
        float4 b00 = ld4(bp + k0),            b01 = ld4(bp + k0 + 4);
        float4 b10 = ld4(bp + 16*ldB + k0),   b11 = ld4(bp + 16*ldB + k0 + 4);
        float4 b20 = ld4(bp + 32*ldB + k0),   b21 = ld4(bp + 32*ldB + k0 + 4);
        float4 b30 = ld4(bp + 48*ldB + k0),   b31 = ld4(bp + 48*ldB + k0 + 4);
        bf16x8 af = cvt8(a0, a1);
        acc[0] = __builtin_amdgcn_mfma_f32_16x16x32_bf16(af, cvt8(b00, b01), acc[0], 0, 0, 0);
        acc[1] = __builtin_amdgcn_mfma_f32_16x16x32_bf16(af, cvt8(b10, b11), acc[1], 0, 0, 0);
        acc[2] = __builtin_amdgcn_mfma_f32_16x16x32_bf16(af, cvt8(b20, b21), acc[2], 0, 0, 0);
        acc[3] = __builtin_amdgcn_mfma_f32_16x16x32_bf16(af, cvt8(b30, b31), acc[3], 0, 0, 0);
    }
}

// ---------------- K1: q/k/v projections (192) + Wr transpose (64) ----------------
__global__ __launch_bounds__(256) void k_front(
        const float* __restrict__ x,
        const float* __restrict__ Wq, const float* __restrict__ Wk, const float* __restrict__ Wv,
        const float* __restrict__ bq, const float* __restrict__ bk, const float* __restrict__ bv,
        const float* __restrict__ Wr,
        const float* __restrict__ u, const float* __restrict__ vbv, const float* __restrict__ br,
        float* __restrict__ qw, float* __restrict__ kw, float* __restrict__ vw,
        float* __restrict__ wrt,
        float* __restrict__ c_ws, float* __restrict__ uk_ws, float* __restrict__ vwr_ws) {
    int id = blockIdx.x;
    int t = threadIdx.x;
    if (id < 192) {
        int mat = id >> 6, rem = id & 63;
        int m0 = (rem >> 3) * 64, n0 = (rem & 7) * 64;
        const float* W   = (mat == 0) ? Wq : (mat == 1) ? Wk : Wv;
        const float* bias= (mat == 0) ? bq : (mat == 1) ? bk : bv;
        float* out       = (mat == 0) ? qw : (mat == 1) ? kw : vw;
        int wv = t >> 6, lane = t & 63;
        f32x4 acc[4] = {{0,0,0,0},{0,0,0,0},{0,0,0,0},{0,0,0,0}};
        mfma_tile(x + (m0 + wv * 16) * 512, 512, W + n0 * 512, 512, 512, lane, acc);
        int h = n0 >> 6;
        int col = lane & 15, rbase = (lane >> 4) * 4;
        float rpart[4] = {0, 0, 0, 0};
#pragma unroll
        for (int c = 0; c < 4; c++) {
            int d = c * 16 + col;
            float bv_ = bias[n0 + d];
            float vbd = vbv[n0 + d];
            float brd = br[n0 + d];
            float ud  = u[n0 + d];
#pragma unroll
            for (int r = 0; r < 4; r++) {
                int m = m0 + wv * 16 + rbase + r;
                int b = m >> 8, i = m & 255;
                float val = acc[c][r] + bv_;
                out[((b * 8 + h) * 256 + i) * 64 + d] = val;
                if (mat == 0) rpart[r] += (val + vbd) * brd;
                else if (mat == 1) rpart[r] += val * ud;
            }
        }
        if (mat < 2) {
#pragma unroll
            for (int msk = 1; msk < 16; msk <<= 1) {
#pragma unroll
                for (int r = 0; r < 4; r++) rpart[r] += __shfl_xor(rpart[r], msk, 64);
            }
            if (col == 0) {
                float* dst = (mat == 0) ? c_ws : uk_ws;
#pragma unroll
                for (int r = 0; r < 4; r++) {
                    int m = m0 + wv * 16 + rbase + r;
                    int b = m >> 8, i = m & 255;
                    dst[(b * 8 + h) * 256 + i] = rpart[r];
                }
            }
        }
    } else {
        __shared__ float tile[64][65];
        __shared__ float vpart[4][64];
        int id2 = id - 192;
        int n0 = (id2 >> 3) * 64, k0 = (id2 & 7) * 64;
        int h = n0 >> 6;
        int tx = t & 63, ty = t >> 6;
#pragma unroll
        for (int r = 0; r < 16; r++) {
            int row = ty * 16 + r;
            tile[row][tx] = Wr[(n0 + row) * 512 + k0 + tx];
        }
        __syncthreads();
#pragma unroll
        for (int r = 0; r < 16; r++) {
            int row = ty * 16 + r;
            wrt[(k0 + row) * 512 + n0 + tx] = tile[tx][row];
        }
        float s = 0.f;
#pragma unroll
        for (int r = 0; r < 16; r++) s += vbv[n0 + ty * 16 + r] * tile[ty * 16 + r][tx];
        vpart[ty][tx] = s;
        __syncthreads();
        if (t < 64) vwr_ws[h * 512 + k0 + t] = vpart[0][t] + vpart[1][t] + vpart[2][t] + vpart[3][t];
    }
}

// ---------------- K2: w-GEMM (512) + ac-GEMM (256), pure MFMA ----------------
__global__ __launch_bounds__(256) void k_mid(
        const float* __restrict__ qw, const float* __restrict__ kw,
        const float* __restrict__ wrt,
        const float* __restrict__ c_ws, const float* __restrict__ uk_ws,
        const float* __restrict__ vwr_ws,
        float* __restrict__ w_ws, float* __restrict__ ac_ws) {
    int id = blockIdx.x;
    int t = threadIdx.x, wv = t >> 6, lane = t & 63;
    int col = lane & 15, rbase = (lane >> 4) * 4;
    if (id < 512) {
        int h = id >> 6, rem = id & 63;
        int m0 = (rem >> 3) * 64, n0 = (rem & 7) * 64;
        int b = m0 >> 8, i0 = m0 & 255;
        f32x4 acc[4] = {{0,0,0,0},{0,0,0,0},{0,0,0,0},{0,0,0,0}};
        mfma_tile(qw + ((b * 8 + h) * 256 + i0 + wv * 16) * 64, 64,
                  wrt + (size_t)n0 * 512 + h * 64, 512, 64, lane, acc);
#pragma unroll
        for (int c = 0; c < 4; c++) {
            int n = n0 + c * 16 + col;
            float vw_ = vwr_ws[h * 512 + n];
#pragma unroll
            for (int r = 0; r < 4; r++) {
                int m = m0 + wv * 16 + rbase + r;
                w_ws[((size_t)m * 8 + h) * 512 + n] = acc[c][r] + vw_;
            }
        }
    } else {
        int id2 = id - 512;
        int bh = id2 >> 4, rem2 = id2 & 15;
        int b = bh >> 3, h = bh & 7;
        int i0 = (rem2 >> 2) * 64, j0 = (rem2 & 3) * 64;
        f32x4 acc[4] = {{0,0,0,0},{0,0,0,0},{0,0,0,0},{0,0,0,0}};
        mfma_tile(qw + ((b * 8 + h) * 256 + i0 + wv * 16) * 64, 64,
                  kw + ((b * 8 + h) * 256 + j0) * 64, 64, 64, lane, acc);
#pragma unroll
        for (int c = 0; c < 4; c++) {
            int j = j0 + c * 16 + col;
            float ukv = uk_ws[(b * 8 + h) * 256 + j];
#pragma unroll
            for (int r = 0; r < 4; r++) {
                int ii = i0 + wv * 16 + rbase + r;
                float ci = c_ws[(b * 8 + h) * 256 + ii];
                ac_ws[((size_t)(b * 256 + ii) * 8 + h) * 256 + j] = acc[c][r] + ukv + ci;
            }
        }
    }
}

// ---------------- K3: fused B_D + softmax + PV; conflict-free LDS, 48 KB ----------------
// grid 512 = (b,i), block 512 = 8 waves; wave wv owns j-rows [32wv, 32wv+32)
__global__ __launch_bounds__(512, 4) void k_attn(
        const float* __restrict__ pos, const float* __restrict__ w_ws,
        const float* __restrict__ ac_ws, const float* __restrict__ vw,
        const int* __restrict__ seq_mask, float* __restrict__ ctx) {
    int bi = blockIdx.x;
    int b = bi >> 8, i = bi & 255;
    int t = threadIdx.x;
    int wv = t >> 6, lane = t & 63;
    __shared__ unsigned short wl[16 * 512];      // 16 KB? -> [16 estep][64 slots][8] = 16KB
    __shared__ float sc[8][256];                 // 8 KB
    __shared__ unsigned short stage[8][2048];    // 32 KB: per-wave 16 rows x 128 e; PV overlay

    // stage w (f32 -> bf16) into wl in MFMA B-fragment order:
    // value w[h][e] -> estep = e>>5, slot = h + 16*((e>>3)&3), elem = e&7
    // thread t: h = t>>6, covers e0 = (t&63)*8 .. +8  => one 16B slot
    {
        int h = t >> 6;
        int j = t & 63;
        const float* src = w_ws + ((size_t)bi * 8 + h) * 512 + j * 8;
        float4 a = ld4(src);
        float4 c = ld4(src + 4);
        char* dst = reinterpret_cast<char*>(wl) + (j >> 2) * 1024 + ((j & 3) * 16 + h) * 16;
        *reinterpret_cast<ushort4*>(dst)     = cvt4u(a);
        *reinterpret_cast<ushort4*>(dst + 8) = cvt4u(c);
    }
    __syncthreads();

    const float* pb = pos + (size_t)bi * (256 * 512);
    int jbase = wv * 32;
    char* sb = reinterpret_cast<char*>(&stage[wv][0]);
    int arow = lane & 15;
    // per-lane constant pieces
    int a_off = arow * 256 + (lane >> 4) * 16;                 // A-frag read base (bytes)
    int b_off = (lane & 15) * 16 + (lane >> 4) * 256;          // B-frag read base (bytes)
    const char* wlc = reinterpret_cast<const char*>(wl);

#pragma unroll
    for (int jt = 0; jt < 2; jt++) {
        f32x4 acc = {0, 0, 0, 0};
#pragma unroll
        for (int eh = 0; eh < 4; eh++) {
            // stage 16 rows x 128 e: each instr loads 2 rows (2 x 512B segments)
            const float* src = pb + (size_t)(jbase + jt * 16 + (lane >> 5)) * 512
                             + eh * 128 + (lane & 31) * 4;
            float4 tmp[8];
#pragma unroll
            for (int s = 0; s < 8; s++) tmp[s] = ld4(src + (size_t)s * 2 * 512);
#pragma unroll
            for (int s = 0; s < 8; s++) {
                int row = (lane >> 5) + s * 2;
                *reinterpret_cast<ushort4*>(sb + row * 256 + (lane & 31) * 8) = cvt4u(tmp[s]);
            }
            // 4 accumulating MFMA e-steps over this 128-e chunk
#pragma unroll
            for (int es = 0; es < 4; es++) {
                bf16x8 af = *reinterpret_cast<const bf16x8*>(sb + a_off + es * 64);
                int estep = eh * 4 + es;
                bf16x8 bf = *reinterpret_cast<const bf16x8*>(wlc + estep * 1024 + b_off);
                acc = __builtin_amdgcn_mfma_f32_16x16x32_bf16(af, bf, acc, 0, 0, 0);
            }
        }
        int h = lane & 15;
        int rbase = (lane >> 4) * 4;
        if (h < 8) {
#pragma unroll
            for (int r = 0; r < 4; r++) sc[h][jbase + jt * 16 + rbase + r] = acc[r];
        }
    }
    __syncthreads();

    // softmax: wave wv owns head h = wv
    {
        int h = wv;
        const float* acrow = ac_ws + ((b * 256 + i) * 8 + h) * 256;
        float vals[4];
        float mx = -INFINITY;
#pragma unroll
        for (int r = 0; r < 4; r++) {
            int j = lane + r * 64;
            float s = (sc[h][j] + acrow[j]) * 0.125f;
            if (seq_mask[b * 256 + j] == 0) s = -1e15f;
            vals[r] = s;
            mx = fmaxf(mx, s);
        }
#pragma unroll
        for (int m = 32; m >= 1; m >>= 1) mx = fmaxf(mx, __shfl_xor(mx, m, 64));
        float sum = 0.f;
#pragma unroll
        for (int r = 0; r < 4; r++) { vals[r] = __expf(vals[r] - mx); sum += vals[r]; }
#pragma unroll
        for (int m = 32; m >= 1; m >>= 1) sum += __shfl_xor(sum, m, 64);
        float inv = 1.0f / sum;
#pragma unroll
        for (int r = 0; r < 4; r++) sc[h][lane + r * 64] = vals[r] * inv;
    }
    // no barrier: PV uses wave-private data (sc row h by wave h; part region h)

    float4* part = reinterpret_cast<float4*>(&stage[0][0]);
    {
        int h = wv;
        int d4 = (lane & 15) * 4;
        int js = lane >> 4;
        const float* vbase = vw + (size_t)(b * 8 + h) * 256 * 64 + d4;
        float4 acc = {0, 0, 0, 0};
#pragma unroll 2
        for (int r = 0; r < 64; r += 4) {
            int j = js * 64 + r;
            float p0 = sc[h][j + 0], p1 = sc[h][j + 1];
            float p2 = sc[h][j + 2], p3 = sc[h][j + 3];
            float4 v0 = ld4(vbase + (size_t)(j + 0) * 64);
            float4 v1 = ld4(vbase + (size_t)(j + 1) * 64);
            float4 v2 = ld4(vbase + (size_t)(j + 2) * 64);
            float4 v3 = ld4(vbase + (size_t)(j + 3) * 64);
            fma4(acc, p0, v0); fma4(acc, p1, v1);
            fma4(acc, p2, v2); fma4(acc, p3, v3);
        }
        part[(h * 4 + js) * 16 + (lane & 15)] = acc;
    }
    {
        int h = wv;
        if ((lane >> 4) == 0) {
            int l = lane & 15;
            float4 a0 = part[(h * 4 + 0) * 16 + l], a1 = part[(h * 4 + 1) * 16 + l];
            float4 a2 = part[(h * 4 + 2) * 16 + l], a3 = part[(h * 4 + 3) * 16 + l];
            float4 o;
            o.x = a0.x + a1.x + a2.x + a3.x;
            o.y = a0.y + a1.y + a2.y + a3.y;
            o.z = a0.z + a1.z + a2.z + a3.z;
            o.w = a0.w + a1.w + a2.w + a3.w;
            st4(ctx + (size_t)(b * 256 + i) * 512 + h * 64 + l * 4, o);
        }
    }
}

// ---------------- K4: FFN GEMM + bias + residual ----------------
__global__ __launch_bounds__(256) void k_ffn(
        const float* __restrict__ A, const float* __restrict__ Wf,
        const float* __restrict__ bias, const float* __restrict__ resid,
        float* __restrict__ outp) {
    int m0 = blockIdx.x * 64, n0 = blockIdx.y * 64;
    int t = threadIdx.x, wv = t >> 6, lane = t & 63;
    f32x4 acc[4] = {{0,0,0,0},{0,0,0,0},{0,0,0,0},{0,0,0,0}};
    mfma_tile(A + (m0 + wv * 16) * 512, 512, Wf + n0 * 512, 512, 512, lane, acc);
    int col = lane & 15, rbase = (lane >> 4) * 4;
#pragma unroll
    for (int c = 0; c < 4; c++) {
        int n = n0 + c * 16 + col;
        float bv_ = bias[n];
#pragma unroll
        for (int r = 0; r < 4; r++) {
            int m = m0 + wv * 16 + rbase + r;
            outp[m * 512 + n] = acc[c][r] + bv_ + resid[m * 512 + n];
        }
    }
}

// ---------------- K5: LayerNorm ----------------
__global__ __launch_bounds__(256) void k_ln(
        const float* __restrict__ tmp, const float* __restrict__ gamma,
        const float* __restrict__ beta, float* __restrict__ out) {
    int m = blockIdx.x, t = threadIdx.x;
    int wv = t >> 6, lane = t & 63;
    float2 xv = *reinterpret_cast<const float2*>(&tmp[m * 512 + t * 2]);
    __shared__ float red[4];
    float s = xv.x + xv.y;
#pragma unroll
    for (int k = 32; k >= 1; k >>= 1) s += __shfl_xor(s, k, 64);
    if (lane == 0) red[wv] = s;
    __syncthreads();
    float mu = (red[0] + red[1] + red[2] + red[3]) * (1.0f / 512.0f);
    __syncthreads();
    float dx = xv.x - mu, dy = xv.y - mu;
    float vs = dx * dx + dy * dy;
#pragma unroll
    for (int k = 32; k >= 1; k >>= 1) vs += __shfl_xor(vs, k, 64);
    if (lane == 0) red[wv] = vs;
    __syncthreads();
    float var = (red[0] + red[1] + red[2] + red[3]) * (1.0f / 512.0f);
    float rstd = rsqrtf(var + 1e-12f);
    float2 g = *reinterpret_cast<const float2*>(&gamma[t * 2]);
    float2 be = *reinterpret_cast<const float2*>(&beta[t * 2]);
    float2 o;
    o.x = dx * rstd * g.x + be.x;
    o.y = dy * rstd * g.y + be.y;
    *reinterpret_cast<float2*>(&out[m * 512 + t * 2]) = o;
}

extern "C" void kernel_launch(void* const* d_in, const int* in_sizes, int n_in,
                              void* d_out, int out_size, void* d_ws, size_t ws_size,
                              hipStream_t stream) {
    const float* x     = (const float*)d_in[0];
    const float* pos   = (const float*)d_in[1];
    const int*   smask = (const int*)d_in[2];
    const float* Wq = (const float*)d_in[3];
    const float* bq = (const float*)d_in[4];
    const float* Wk = (const float*)d_in[5];
    const float* bk = (const float*)d_in[6];
    const float* Wv = (const float*)d_in[7];
    const float* bv = (const float*)d_in[8];
    const float* Wr = (const float*)d_in[9];
    const float* br = (const float*)d_in[10];
    const float* u  = (const float*)d_in[11];
    const float* vb = (const float*)d_in[12];
    const float* Wf = (const float*)d_in[13];
    const float* bf = (const float*)d_in[14];
    const float* gamma = (const float*)d_in[15];
    const float* beta  = (const float*)d_in[16];
    float* out = (float*)d_out;

    float* ws = (float*)d_ws;
    float* q_ws   = ws;                       // 262144 f
    float* k_ws   = q_ws  + 262144;           // 262144 f
    float* v_ws   = k_ws  + 262144;           // 262144 f
    float* w_ws   = v_ws  + 262144;           // 2097152 f
    float* ac_ws  = w_ws  + 2097152;          // 1048576 f
    float* ctx_ws = ac_ws + 1048576;          // 262144 f
    float* tmp_ws = ctx_ws + 262144;          // 262144 f
    float* wrt_ws = tmp_ws + 262144;          // 262144 f
    float* c_ws   = wrt_ws + 262144;          // 4096 f
    float* uk_ws  = c_ws  + 4096;             // 4096 f
    float* vwr_ws = uk_ws + 4096;             // 4096 f

    k_front<<<dim3(256), 256, 0, stream>>>(x, Wq, Wk, Wv, bq, bk, bv, Wr, u, vb, br,
                                           q_ws, k_ws, v_ws, wrt_ws, c_ws, uk_ws, vwr_ws);
    k_mid<<<dim3(768), 256, 0, stream>>>(q_ws, k_ws, wrt_ws, c_ws, uk_ws, vwr_ws, w_ws, ac_ws);
    k_attn<<<dim3(512), 512, 0, stream>>>(pos, w_ws, ac_ws, v_ws, smask, ctx_ws);
    k_ffn<<<dim3(8, 8), 256, 0, stream>>>(ctx_ws, Wf, bf, x, tmp_ws);
    k_ln<<<dim3(512), 256, 0, stream>>>(tmp_ws, gamma, beta, out);
}

// Round 14
// 103.137 us; speedup vs baseline: 1.3743x; 1.0482x over previous
//
#include <hip/hip_runtime.h>
#include <cmath>

// ROUND 14: R13 anchor (108.1us) + ONE structural change: ffn+LN fused into
// k_attn's epilogue (block (b,i) owns the full 512-col row). k_ffn/k_ln
// removed; Wf transposed in k_front (ids 256-319). Launches 5 -> 3.

typedef __bf16 bf16x8 __attribute__((ext_vector_type(8)));
typedef float f32x4 __attribute__((ext_vector_type(4)));

__device__ __forceinline__ float4 ld4(const float* p) { return *reinterpret_cast<const float4*>(p); }
__device__ __forceinline__ void st4(float* p, float4 v) { *reinterpret_cast<float4*>(p) = v; }
__device__ __forceinline__ void fma4(float4& a, float s, const float4& v) {
    a.x = fmaf(s, v.x, a.x); a.y = fmaf(s, v.y, a.y);
    a.z = fmaf(s, v.z, a.z); a.w = fmaf(s, v.w, a.w);
}
__device__ __forceinline__ float dot4(const float4& a, const float4& b) {
    return a.x*b.x + a.y*b.y + a.z*b.z + a.w*b.w;
}
__device__ __forceinline__ unsigned short f2bf(float f) {
    unsigned int x = __float_as_uint(f);
    unsigned int r = x + 0x7FFFu + ((x >> 16) & 1u);
    return (unsigned short)(r >> 16);
}
__device__ __forceinline__ ushort4 cvt4u(float4 a) {
    ushort4 u;
    u.x = f2bf(a.x); u.y = f2bf(a.y); u.z = f2bf(a.z); u.w = f2bf(a.w);
    return u;
}
__device__ __forceinline__ bf16x8 cvt8(float4 a, float4 b) {
    bf16x8 r;
    r[0] = (__bf16)a.x; r[1] = (__bf16)a.y; r[2] = (__bf16)a.z; r[3] = (__bf16)a.w;
    r[4] = (__bf16)b.x; r[5] = (__bf16)b.y; r[6] = (__bf16)b.z; r[7] = (__bf16)b.w;
    return r;
}

// Core 64x64 MFMA tile: 4 waves, wave wv owns rows [wv*16, wv*16+16) x 64 cols.
__device__ __forceinline__ void mfma_tile(
        const float* __restrict__ Abase, int ldA,
        const float* __restrict__ Bbase, int ldB,
        int K, int lane, f32x4 acc[4]) {
    int koff = (lane >> 4) * 8;
    int rr = lane & 15;
    const float* ap = Abase + rr * ldA + koff;
    const float* bp = Bbase + rr * ldB + koff;
#pragma unroll 2
    for (int k0 = 0; k0 < K; k0 += 32) {
        float4 a0  = ld4(ap + k0),            a1  = ld4(ap + k0 + 4);
        float4 b00 = ld4(bp + k0),            b01 = ld4(bp + k0 + 4);
        float4 b10 = ld4(bp + 16*ldB + k0),   b11 = ld4(bp + 16*ldB + k0 + 4);
        float4 b20 = ld4(bp + 32*ldB + k0),   b21 = ld4(bp + 32*ldB + k0 + 4);
        float4 b30 = ld4(bp + 48*ldB + k0),   b31 = ld4(bp + 48*ldB + k0 + 4);
        bf16x8 af = cvt8(a0, a1);
        acc[0] = __builtin_amdgcn_mfma_f32_16x16x32_bf16(af, cvt8(b00, b01), acc[0], 0, 0, 0);
        acc[1] = __builtin_amdgcn_mfma_f32_16x16x32_bf16(af, cvt8(b10, b11), acc[1], 0, 0, 0);
        acc[2] = __builtin_amdgcn_mfma_f32_16x16x32_bf16(af, cvt8(b20, b21), acc[2], 0, 0, 0);
        acc[3] = __builtin_amdgcn_mfma_f32_16x16x32_bf16(af, cvt8(b30, b31), acc[3], 0, 0, 0);
    }
}

// ---------------- K1: q/k/v projections (192) + Wr transpose (64) + Wf transpose (64) ----------------
__global__ __launch_bounds__(256) void k_front(
        const float* __restrict__ x,
        const float* __restrict__ Wq, const float* __restrict__ Wk, const float* __restrict__ Wv,
        const float* __restrict__ bq, const float* __restrict__ bk, const float* __restrict__ bv,
        const float* __restrict__ Wr, const float* __restrict__ Wf,
        const float* __restrict__ u, const float* __restrict__ vbv, const float* __restrict__ br,
        float* __restrict__ qw, float* __restrict__ kw, float* __restrict__ vw,
        float* __restrict__ wrt, float* __restrict__ wft,
        float* __restrict__ c_ws, float* __restrict__ uk_ws, float* __restrict__ vwr_ws) {
    int id = blockIdx.x;
    int t = threadIdx.x;
    if (id < 192) {
        int mat = id >> 6, rem = id & 63;
        int m0 = (rem >> 3) * 64, n0 = (rem & 7) * 64;
        const float* W   = (mat == 0) ? Wq : (mat == 1) ? Wk : Wv;
        const float* bias= (mat == 0) ? bq : (mat == 1) ? bk : bv;
        float* out       = (mat == 0) ? qw : (mat == 1) ? kw : vw;
        int wv = t >> 6, lane = t & 63;
        f32x4 acc[4] = {{0,0,0,0},{0,0,0,0},{0,0,0,0},{0,0,0,0}};
        mfma_tile(x + (m0 + wv * 16) * 512, 512, W + n0 * 512, 512, 512, lane, acc);
        int h = n0 >> 6;
        int col = lane & 15, rbase = (lane >> 4) * 4;
        float rpart[4] = {0, 0, 0, 0};
#pragma unroll
        for (int c = 0; c < 4; c++) {
            int d = c * 16 + col;
            float bv_ = bias[n0 + d];
            float vbd = vbv[n0 + d];
            float brd = br[n0 + d];
            float ud  = u[n0 + d];
#pragma unroll
            for (int r = 0; r < 4; r++) {
                int m = m0 + wv * 16 + rbase + r;
                int b = m >> 8, i = m & 255;
                float val = acc[c][r] + bv_;
                out[((b * 8 + h) * 256 + i) * 64 + d] = val;
                if (mat == 0) rpart[r] += (val + vbd) * brd;
                else if (mat == 1) rpart[r] += val * ud;
            }
        }
        if (mat < 2) {
#pragma unroll
            for (int msk = 1; msk < 16; msk <<= 1) {
#pragma unroll
                for (int r = 0; r < 4; r++) rpart[r] += __shfl_xor(rpart[r], msk, 64);
            }
            if (col == 0) {
                float* dst = (mat == 0) ? c_ws : uk_ws;
#pragma unroll
                for (int r = 0; r < 4; r++) {
                    int m = m0 + wv * 16 + rbase + r;
                    int b = m >> 8, i = m & 255;
                    dst[(b * 8 + h) * 256 + i] = rpart[r];
                }
            }
        }
    } else {
        // transpose: ids 192-255 -> Wr (also vwr); ids 256-319 -> Wf
        __shared__ float tile[64][65];
        __shared__ float vpart[4][64];
        int isWf = (id >= 256);
        int id2 = id - (isWf ? 256 : 192);
        const float* Wsrc = isWf ? Wf : Wr;
        float* Wdst = isWf ? wft : wrt;
        int n0 = (id2 >> 3) * 64, k0 = (id2 & 7) * 64;
        int h = n0 >> 6;
        int tx = t & 63, ty = t >> 6;
#pragma unroll
        for (int r = 0; r < 16; r++) {
            int row = ty * 16 + r;
            tile[row][tx] = Wsrc[(n0 + row) * 512 + k0 + tx];
        }
        __syncthreads();
#pragma unroll
        for (int r = 0; r < 16; r++) {
            int row = ty * 16 + r;
            Wdst[(k0 + row) * 512 + n0 + tx] = tile[tx][row];
        }
        if (!isWf) {
            float s = 0.f;
#pragma unroll
            for (int r = 0; r < 16; r++) s += vbv[n0 + ty * 16 + r] * tile[ty * 16 + r][tx];
            vpart[ty][tx] = s;
            __syncthreads();
            if (t < 64) vwr_ws[h * 512 + k0 + t] = vpart[0][t] + vpart[1][t] + vpart[2][t] + vpart[3][t];
        }
    }
}

// ---------------- K2: w-GEMM (512) + ac-GEMM (256), pure MFMA ----------------
__global__ __launch_bounds__(256) void k_mid(
        const float* __restrict__ qw, const float* __restrict__ kw,
        const float* __restrict__ wrt,
        const float* __restrict__ c_ws, const float* __restrict__ uk_ws,
        const float* __restrict__ vwr_ws,
        float* __restrict__ w_ws, float* __restrict__ ac_ws) {
    int id = blockIdx.x;
    int t = threadIdx.x, wv = t >> 6, lane = t & 63;
    int col = lane & 15, rbase = (lane >> 4) * 4;
    if (id < 512) {
        int h = id >> 6, rem = id & 63;
        int m0 = (rem >> 3) * 64, n0 = (rem & 7) * 64;
        int b = m0 >> 8, i0 = m0 & 255;
        f32x4 acc[4] = {{0,0,0,0},{0,0,0,0},{0,0,0,0},{0,0,0,0}};
        mfma_tile(qw + ((b * 8 + h) * 256 + i0 + wv * 16) * 64, 64,
                  wrt + (size_t)n0 * 512 + h * 64, 512, 64, lane, acc);
#pragma unroll
        for (int c = 0; c < 4; c++) {
            int n = n0 + c * 16 + col;
            float vw_ = vwr_ws[h * 512 + n];
#pragma unroll
            for (int r = 0; r < 4; r++) {
                int m = m0 + wv * 16 + rbase + r;
                w_ws[((size_t)m * 8 + h) * 512 + n] = acc[c][r] + vw_;
            }
        }
    } else {
        int id2 = id - 512;
        int bh = id2 >> 4, rem2 = id2 & 15;
        int b = bh >> 3, h = bh & 7;
        int i0 = (rem2 >> 2) * 64, j0 = (rem2 & 3) * 64;
        f32x4 acc[4] = {{0,0,0,0},{0,0,0,0},{0,0,0,0},{0,0,0,0}};
        mfma_tile(qw + ((b * 8 + h) * 256 + i0 + wv * 16) * 64, 64,
                  kw + ((b * 8 + h) * 256 + j0) * 64, 64, 64, lane, acc);
#pragma unroll
        for (int c = 0; c < 4; c++) {
            int j = j0 + c * 16 + col;
            float ukv = uk_ws[(b * 8 + h) * 256 + j];
#pragma unroll
            for (int r = 0; r < 4; r++) {
                int ii = i0 + wv * 16 + rbase + r;
                float ci = c_ws[(b * 8 + h) * 256 + ii];
                ac_ws[((size_t)(b * 256 + ii) * 8 + h) * 256 + j] = acc[c][r] + ukv + ci;
            }
        }
    }
}

// ---------------- K3: fused B_D + softmax + PV + FFN + LayerNorm ----------------
// grid 512 = (b,i), block 512 = 8 waves; wave wv owns j-rows [32wv, 32wv+32)
__global__ __launch_bounds__(512, 4) void k_attn(
        const float* __restrict__ pos, const float* __restrict__ w_ws,
        const float* __restrict__ ac_ws, const float* __restrict__ vw,
        const int* __restrict__ seq_mask,
        const float* __restrict__ wft, const float* __restrict__ bf,
        const float* __restrict__ x,
        const float* __restrict__ gamma, const float* __restrict__ beta,
        float* __restrict__ outp) {
    int bi = blockIdx.x;
    int b = bi >> 8, i = bi & 255;
    int t = threadIdx.x;
    int wv = t >> 6, lane = t & 63;
    __shared__ unsigned short wl[16 * 512];      // 16 KB  B-frag order
    __shared__ float sc[8][256];                 // 8 KB
    __shared__ unsigned short stage[8][2048];    // 32 KB; PV partials overlay
    __shared__ float ctxl[512];                  // 2 KB   full ctx row
    __shared__ float lnred[8][2];                // LN cross-wave scratch

    // stage w (f32 -> bf16) into wl in MFMA B-fragment order
    {
        int h = t >> 6;
        int j = t & 63;
        const float* src = w_ws + ((size_t)bi * 8 + h) * 512 + j * 8;
        float4 a = ld4(src);
        float4 c = ld4(src + 4);
        char* dst = reinterpret_cast<char*>(wl) + (j >> 2) * 1024 + ((j & 3) * 16 + h) * 16;
        *reinterpret_cast<ushort4*>(dst)     = cvt4u(a);
        *reinterpret_cast<ushort4*>(dst + 8) = cvt4u(c);
    }
    __syncthreads();

    const float* pb = pos + (size_t)bi * (256 * 512);
    int jbase = wv * 32;
    char* sb = reinterpret_cast<char*>(&stage[wv][0]);
    int arow = lane & 15;
    int a_off = arow * 256 + (lane >> 4) * 16;
    int b_off = (lane & 15) * 16 + (lane >> 4) * 256;
    const char* wlc = reinterpret_cast<const char*>(wl);

#pragma unroll
    for (int jt = 0; jt < 2; jt++) {
        f32x4 acc = {0, 0, 0, 0};
#pragma unroll
        for (int eh = 0; eh < 4; eh++) {
            const float* src = pb + (size_t)(jbase + jt * 16 + (lane >> 5)) * 512
                             + eh * 128 + (lane & 31) * 4;
            float4 tmp[8];
#pragma unroll
            for (int s = 0; s < 8; s++) tmp[s] = ld4(src + (size_t)s * 2 * 512);
#pragma unroll
            for (int s = 0; s < 8; s++) {
                int row = (lane >> 5) + s * 2;
                *reinterpret_cast<ushort4*>(sb + row * 256 + (lane & 31) * 8) = cvt4u(tmp[s]);
            }
#pragma unroll
            for (int es = 0; es < 4; es++) {
                bf16x8 af = *reinterpret_cast<const bf16x8*>(sb + a_off + es * 64);
                int estep = eh * 4 + es;
                bf16x8 bf_ = *reinterpret_cast<const bf16x8*>(wlc + estep * 1024 + b_off);
                acc = __builtin_amdgcn_mfma_f32_16x16x32_bf16(af, bf_, acc, 0, 0, 0);
            }
        }
        int h = lane & 15;
        int rbase = (lane >> 4) * 4;
        if (h < 8) {
#pragma unroll
            for (int r = 0; r < 4; r++) sc[h][jbase + jt * 16 + rbase + r] = acc[r];
        }
    }
    __syncthreads();

    // softmax: wave wv owns head h = wv
    {
        int h = wv;
        const float* acrow = ac_ws + ((b * 256 + i) * 8 + h) * 256;
        float vals[4];
        float mx = -INFINITY;
#pragma unroll
        for (int r = 0; r < 4; r++) {
            int j = lane + r * 64;
            float s = (sc[h][j] + acrow[j]) * 0.125f;
            if (seq_mask[b * 256 + j] == 0) s = -1e15f;
            vals[r] = s;
            mx = fmaxf(mx, s);
        }
#pragma unroll
        for (int m = 32; m >= 1; m >>= 1) mx = fmaxf(mx, __shfl_xor(mx, m, 64));
        float sum = 0.f;
#pragma unroll
        for (int r = 0; r < 4; r++) { vals[r] = __expf(vals[r] - mx); sum += vals[r]; }
#pragma unroll
        for (int m = 32; m >= 1; m >>= 1) sum += __shfl_xor(sum, m, 64);
        float inv = 1.0f / sum;
#pragma unroll
        for (int r = 0; r < 4; r++) sc[h][lane + r * 64] = vals[r] * inv;
    }
    // no barrier: PV uses wave-private data

    // PV: wave = head h = wv -> ctx cols [64h, 64h+64) into LDS ctxl
    float4* part = reinterpret_cast<float4*>(&stage[0][0]);
    {
        int h = wv;
        int d4 = (lane & 15) * 4;
        int js = lane >> 4;
        const float* vbase = vw + (size_t)(b * 8 + h) * 256 * 64 + d4;
        float4 acc = {0, 0, 0, 0};
#pragma unroll 2
        for (int r = 0; r < 64; r += 4) {
            int j = js * 64 + r;
            float p0 = sc[h][j + 0], p1 = sc[h][j + 1];
            float p2 = sc[h][j + 2], p3 = sc[h][j + 3];
            float4 v0 = ld4(vbase + (size_t)(j + 0) * 64);
            float4 v1 = ld4(vbase + (size_t)(j + 1) * 64);
            float4 v2 = ld4(vbase + (size_t)(j + 2) * 64);
            float4 v3 = ld4(vbase + (size_t)(j + 3) * 64);
            fma4(acc, p0, v0); fma4(acc, p1, v1);
            fma4(acc, p2, v2); fma4(acc, p3, v3);
        }
        part[(h * 4 + js) * 16 + (lane & 15)] = acc;
    }
    {
        int h = wv;
        if ((lane >> 4) == 0) {
            int l = lane & 15;
            float4 a0 = part[(h * 4 + 0) * 16 + l], a1 = part[(h * 4 + 1) * 16 + l];
            float4 a2 = part[(h * 4 + 2) * 16 + l], a3 = part[(h * 4 + 3) * 16 + l];
            float4 o;
            o.x = a0.x + a1.x + a2.x + a3.x;
            o.y = a0.y + a1.y + a2.y + a3.y;
            o.z = a0.z + a1.z + a2.z + a3.z;
            o.w = a0.w + a1.w + a2.w + a3.w;
            st4(&ctxl[h * 64 + l * 4], o);
        }
    }
    __syncthreads();

    // FFN + residual + LayerNorm: wave wv owns out cols [64wv, 64wv+64)
    {
        int n = wv * 64 + lane;
        const float* wcol = wft + n;
        float acc = 0.f;
#pragma unroll 4
        for (int k0 = 0; k0 < 512; k0 += 8) {
            float4 c0 = ld4(&ctxl[k0]);
            float4 c1 = ld4(&ctxl[k0 + 4]);
            acc = fmaf(c0.x, wcol[(size_t)(k0 + 0) * 512], acc);
            acc = fmaf(c0.y, wcol[(size_t)(k0 + 1) * 512], acc);
            acc = fmaf(c0.z, wcol[(size_t)(k0 + 2) * 512], acc);
            acc = fmaf(c0.w, wcol[(size_t)(k0 + 3) * 512], acc);
            acc = fmaf(c1.x, wcol[(size_t)(k0 + 4) * 512], acc);
            acc = fmaf(c1.y, wcol[(size_t)(k0 + 5) * 512], acc);
            acc = fmaf(c1.z, wcol[(size_t)(k0 + 6) * 512], acc);
            acc = fmaf(c1.w, wcol[(size_t)(k0 + 7) * 512], acc);
        }
        float v = acc + bf[n] + x[(size_t)(b * 256 + i) * 512 + n];
        // LN over the 512-col row: wave-local reduce then cross-wave
        float s = v, q = v * v;
#pragma unroll
        for (int m = 32; m >= 1; m >>= 1) {
            s += __shfl_xor(s, m, 64);
            q += __shfl_xor(q, m, 64);
        }
        if (lane == 0) { lnred[wv][0] = s; lnred[wv][1] = q; }
        __syncthreads();
        float ts = 0.f, tq = 0.f;
#pragma unroll
        for (int w2 = 0; w2 < 8; w2++) { ts += lnred[w2][0]; tq += lnred[w2][1]; }
        float mu = ts * (1.0f / 512.0f);
        float var = tq * (1.0f / 512.0f) - mu * mu;
        float rstd = rsqrtf(var + 1e-12f);
        outp[(size_t)(b * 256 + i) * 512 + n] = (v - mu) * rstd * gamma[n] + beta[n];
    }
}

extern "C" void kernel_launch(void* const* d_in, const int* in_sizes, int n_in,
                              void* d_out, int out_size, void* d_ws, size_t ws_size,
                              hipStream_t stream) {
    const float* x     = (const float*)d_in[0];
    const float* pos   = (const float*)d_in[1];
    const int*   smask = (const int*)d_in[2];
    const float* Wq = (const float*)d_in[3];
    const float* bq = (const float*)d_in[4];
    const float* Wk = (const float*)d_in[5];
    const float* bk = (const float*)d_in[6];
    const float* Wv = (const float*)d_in[7];
    const float* bv = (const float*)d_in[8];
    const float* Wr = (const float*)d_in[9];
    const float* br = (const float*)d_in[10];
    const float* u  = (const float*)d_in[11];
    const float* vb = (const float*)d_in[12];
    const float* Wf = (const float*)d_in[13];
    const float* bf = (const float*)d_in[14];
    const float* gamma = (const float*)d_in[15];
    const float* beta  = (const float*)d_in[16];
    float* out = (float*)d_out;

    float* ws = (float*)d_ws;
    float* q_ws   = ws;                       // 262144 f
    float* k_ws   = q_ws  + 262144;           // 262144 f
    float* v_ws   = k_ws  + 262144;           // 262144 f
    float* w_ws   = v_ws  + 262144;           // 2097152 f
    float* ac_ws  = w_ws  + 2097152;          // 1048576 f
    float* wrt_ws = ac_ws + 1048576;          // 262144 f
    float* wft_ws = wrt_ws + 262144;          // 262144 f
    float* c_ws   = wft_ws + 262144;          // 4096 f
    float* uk_ws  = c_ws  + 4096;             // 4096 f
    float* vwr_ws = uk_ws + 4096;             // 4096 f

    k_front<<<dim3(320), 256, 0, stream>>>(x, Wq, Wk, Wv, bq, bk, bv, Wr, Wf, u, vb, br,
                                           q_ws, k_ws, v_ws, wrt_ws, wft_ws,
                                           c_ws, uk_ws, vwr_ws);
    k_mid<<<dim3(768), 256, 0, stream>>>(q_ws, k_ws, wrt_ws, c_ws, uk_ws, vwr_ws, w_ws, ac_ws);
    k_attn<<<dim3(512), 512, 0, stream>>>(pos, w_ws, ac_ws, v_ws, smask,
                                          wft_ws, bf, x, gamma, beta, out);
}